// Round 8
// baseline (306.340 us; speedup 1.0000x reference)
//
#include <hip/hip_runtime.h>

typedef float v2f __attribute__((ext_vector_type(2)));
typedef float v4f __attribute__((ext_vector_type(4)));
typedef __fp16 v2h __attribute__((ext_vector_type(2)));

#define TT 1024
#define NIN 6
#define NN 64
#define CHUNK 32
#define NCHUNK 32
#define SCALE 0.09486832980505137f  // sqrt(2*alpha*sigma_rec^2)

__device__ __forceinline__ v2f pk_fma(v2f a, v2f b, v2f c) {
  return __builtin_elementwise_fma(a, b, c);  // -> v_pk_fma_f32
}
__device__ __forceinline__ v2h h2_from_i(int i) { return __builtin_bit_cast(v2h, i); }
__device__ __forceinline__ int i_from_h2(v2h h) { return __builtin_bit_cast(int, h); }

template <int CTRL>
__device__ __forceinline__ int dppmov(int src) {
  return __builtin_amdgcn_update_dpp(0, src, CTRL, 0xF, 0xF, true);
}

// 6-stage in-register all-gather: each lane ends with all 64 wave values as
// 32 packed-f16 regs, in a per-lane order sigma_l. Pure VALU (DPP + permlane
// swaps) -- no LDS, no SGPRs, no readlane. sigma_l is NOT derived analytically:
// we run this same network on payload=laneid at startup and gather the weights
// to match, so any half-swap semantics of the permlane ops is self-consistent.
__device__ __forceinline__ void gather64(float v, int g[32]) {
  const int part = dppmov<0xB1>(__float_as_int(v));  // quad_perm[1,0,3,2]: lane^1
  const int p0 = i_from_h2(__builtin_amdgcn_cvt_pkrtz(v, __int_as_float(part)));
  g[0] = p0;                      // 2 comps (own quad pair)
  g[1] = dppmov<0x4E>(p0);        // quad_perm[2,3,0,1]: lane^2 -> 4 comps
  g[2] = dppmov<0x124>(g[0]);     // row_ror:4 -> neighbor quad
  g[3] = dppmov<0x124>(g[1]);
  g[4] = dppmov<0x128>(g[0]);     // row_ror:8 -> remaining quads
  g[5] = dppmov<0x128>(g[1]);
  g[6] = dppmov<0x128>(g[2]);
  g[7] = dppmov<0x128>(g[3]);     // 8 regs = own 16-lane row's comps
#pragma unroll
  for (int i = 0; i < 8; ++i) {   // 16-lane half exchange; keep BOTH outputs
    auto r = __builtin_amdgcn_permlane16_swap(g[i], g[i], false, false);
    g[i] = r[0]; g[8 + i] = r[1];
  }                               // 16 regs = own 32-lane half's comps
#pragma unroll
  for (int i = 0; i < 16; ++i) {  // 32-lane half exchange
    auto r = __builtin_amdgcn_permlane32_swap(g[i], g[i], false, false);
    g[i] = r[0]; g[16 + i] = r[1];
  }                               // 32 regs = all 64 comps (order sigma_l)
}

typedef const __attribute__((address_space(1))) unsigned int gu32;
typedef __attribute__((address_space(3))) unsigned int lu32;

__global__ void __launch_bounds__(64) rnn_scan_kernel(
    const float* __restrict__ u, const float* __restrict__ noise,
    const float* __restrict__ Wrec, const float* __restrict__ Win,
    float* __restrict__ out) {
  const int b = blockIdx.x;
  const int n = threadIdx.x;  // lane owns state component n

  __shared__ __align__(16) float smHist[CHUNK][NN];      // 8 KB (store path)
  __shared__ __align__(16) float smNz[2][CHUNK * NN];    // noise chunks (2x8KB)
  __shared__ __align__(16) float smU[2][CHUNK * NIN];    // u chunks (2x768B)

  const float* nzg = noise + (size_t)b * TT * NN;
  const float* ug  = u + (size_t)b * TT * NIN;
  float* outB = out + (size_t)b * TT * NN;

  // ---- stage chunk 0 (latency hidden behind weight setup below)
#pragma unroll
  for (int i = 0; i < 8; ++i)
    __builtin_amdgcn_global_load_lds((gu32*)(nzg + i * 256 + n * 4),
                                     (lu32*)(&smNz[0][i * 256]), 16, 0, 0);
#pragma unroll
  for (int j = 0; j < 3; ++j)
    __builtin_amdgcn_global_load_lds((gu32*)(ug + j * 64 + n),
                                     (lu32*)(&smU[0][j * 64]), 4, 0, 0);

  // ---- learn sigma_l: run the network on payload = lane index, then gather
  // W_rec row n in that order so in-loop dots line up by construction.
  int gidx[32];
  gather64((float)n, gidx);
  v2h w16[32];
  const float* wrow = Wrec + n * NN;
#pragma unroll
  for (int j = 0; j < 32; ++j) {
    const v2h ij = h2_from_i(gidx[j]);
    const int k0 = (int)(float)ij[0];
    const int k1 = (int)(float)ij[1];
    w16[j] = __builtin_amdgcn_cvt_pkrtz(wrow[k0], wrow[k1]);
  }
  v2f win2[3];
#pragma unroll
  for (int j = 0; j < 3; ++j)
    win2[j] = v2f{Win[n * NIN + 2 * j + 0], Win[n * NIN + 2 * j + 1]};

  float s = 0.0f;
  outB[n] = 0.0f;  // states[:,0,:] = 0

  // Drain once -> clean vmcnt accounting for the hand-counted waits below.
  asm volatile("s_waitcnt vmcnt(0)" ::: "memory");
  __builtin_amdgcn_sched_barrier(0);

  for (int c = 0; c < NCHUNK; ++c) {
    const int buf = c & 1;

    if (c + 1 < NCHUNK) {
      const float* ng = nzg + (size_t)(c + 1) * CHUNK * NN;
      const float* gg = ug + (size_t)(c + 1) * CHUNK * NIN;
      float* nl = &smNz[buf ^ 1][0];
      float* ul = &smU[buf ^ 1][0];
#pragma unroll
      for (int i = 0; i < 8; ++i)
        __builtin_amdgcn_global_load_lds((gu32*)(ng + i * 256 + n * 4),
                                         (lu32*)(nl + i * 256), 16, 0, 0);
#pragma unroll
      for (int j = 0; j < 3; ++j)
        __builtin_amdgcn_global_load_lds((gu32*)(gg + j * 64 + n),
                                         (lu32*)(ul + j * 64), 4, 0, 0);
      // Outstanding (oldest->newest): 11 loads(chunk c) + 8 stores(chunk c-1
      // epilogue) + 11 loads(chunk c+1); vmcnt retires in issue order.
      asm volatile("s_waitcnt vmcnt(19)" ::: "memory");
    } else {
      asm volatile("s_waitcnt vmcnt(8)" ::: "memory");
    }
    __builtin_amdgcn_sched_barrier(0);

    const float* nzL = &smNz[buf][0] + n;  // per-lane column
    const float* uL  = &smU[buf][0];       // uniform rows

#pragma unroll 4
    for (int st = 0; st < CHUNK; ++st) {
      // bias reads issue at step-top; consumed ~200cyc later at the merge.
      const float nzc = nzL[st * NN];                 // ds_read_b32
      const v2f* u2p = (const v2f*)(uL + st * NIN);   // 3x ds_read_b64 bcast
      v2f uacc = pk_fma(u2p[0], win2[0], v2f{SCALE * nzc, 0.0f});
      uacc = pk_fma(u2p[1], win2[1], uacc);
      uacc = pk_fma(u2p[2], win2[2], uacc);

      // all-gather s across the wave (pure VALU), then 32 VGPRxVGPR dots.
      int g[32];
      gather64(s, g);
      float acc[8];
#pragma unroll
      for (int j = 0; j < 8; ++j)
        acc[j] = __builtin_amdgcn_fdot2(h2_from_i(g[j]), w16[j], 0.0f, false);
#pragma unroll
      for (int j = 8; j < 32; ++j)
        acc[j & 7] =
            __builtin_amdgcn_fdot2(h2_from_i(g[j]), w16[j], acc[j & 7], false);

      float pre = ((acc[0] + acc[1]) + (acc[2] + acc[3])) +
                  ((acc[4] + acc[5]) + (acc[6] + acc[7]));
      pre += uacc.x + uacc.y;
      const float r = fmaxf(pre, 0.0f);
      s = fmaf(0.2f, r, 0.8f * s);
      smHist[st][n] = s;  // store path only (off the recurrence chain)
    }

    // ---- chunk epilogue: dump 32 state rows (output rows 32c+1..32c+32).
    v4f st4[8];
    const float* hbase = &smHist[0][0] + (n >> 4) * NN + (n & 15) * 4;
#pragma unroll
    for (int i = 0; i < 8; ++i)
      st4[i] = *(const v4f*)(hbase + i * 4 * NN);       // 8x ds_read_b128

    float* gp = outB + (size_t)(c * CHUNK + 1) * NN + (n >> 4) * NN + (n & 15) * 4;
    if (c + 1 < NCHUNK) {
#pragma unroll
      for (int i = 0; i < 8; ++i)
        *(v4f*)(gp + (size_t)i * 4 * NN) = st4[i];      // 8x store_dwordx4
    } else {
      // last chunk: rows 993..1023 only (row 1024 doesn't exist)
#pragma unroll
      for (int i = 0; i < 7; ++i)
        *(v4f*)(gp + (size_t)i * 4 * NN) = st4[i];
      if (n < 48)  // rows 1021..1023
        *(v4f*)(gp + (size_t)7 * 4 * NN) = st4[7];
    }
  }
}

extern "C" void kernel_launch(void* const* d_in, const int* in_sizes, int n_in,
                              void* d_out, int out_size, void* d_ws, size_t ws_size,
                              hipStream_t stream) {
  const float* u     = (const float*)d_in[0];
  const float* noise = (const float*)d_in[1];
  const float* Wrec  = (const float*)d_in[2];
  const float* Win   = (const float*)d_in[3];
  float* out = (float*)d_out;

  const int B = in_sizes[0] / (TT * NIN);  // 512
  hipLaunchKernelGGL(rnn_scan_kernel, dim3(B), dim3(64), 0, stream,
                     u, noise, Wrec, Win, out);
}

// Round 9
// 239.094 us; speedup vs baseline: 1.2813x; 1.2813x over previous
//
#include <hip/hip_runtime.h>

typedef float v2f __attribute__((ext_vector_type(2)));
typedef float v4f __attribute__((ext_vector_type(4)));
typedef __fp16 v2h __attribute__((ext_vector_type(2)));

#define TT 1024
#define NIN 6
#define NN 64
#define CHUNK 32
#define NCHUNK 32
#define SCALE 0.09486832980505137f  // sqrt(2*alpha*sigma_rec^2)

__device__ __forceinline__ v2h h2_from_i(int i) { return __builtin_bit_cast(v2h, i); }
__device__ __forceinline__ int i_from_h2(v2h h) { return __builtin_bit_cast(int, h); }

template <int CTRL>
__device__ __forceinline__ float dppf(float x) {
  return __int_as_float(
      __builtin_amdgcn_update_dpp(0, __float_as_int(x), CTRL, 0xF, 0xF, true));
}

typedef const __attribute__((address_space(1))) unsigned int gu32;
typedef __attribute__((address_space(3))) unsigned int lu32;

// 2-D decomposition: lane l = (g = l>>2, h = l&3).
//   - lane owns OUTPUT rows 4g..4g+3 over K-slice 16h..16h+15 (32 dot2)
//   - reduce over h: quad_perm DPP xor1+xor2 (pure VALU, semantics-certain)
//   - lerp is local (lane's own previous outputs)
//   - state redistribution: 8 parallel ds_bpermute of packed-f16 pairs
//     (ONE DS hop on the recurrence; addresses loop-invariant)
__global__ void __launch_bounds__(64) rnn_scan_kernel(
    const float* __restrict__ u, const float* __restrict__ noise,
    const float* __restrict__ Wrec, const float* __restrict__ Win,
    float* __restrict__ out) {
  const int b = blockIdx.x;
  const int l = threadIdx.x;
  const int g = l >> 2;   // output group: rows 4g..4g+3
  const int h = l & 3;    // k group: cols 16h..16h+15

  __shared__ __align__(16) float smHist[CHUNK][NN];      // 8 KB (store path)
  __shared__ __align__(16) float smNz[2][CHUNK * NN];    // noise chunks (2x8KB)
  __shared__ __align__(16) float smU[2][CHUNK * NIN];    // u chunks (2x768B)

  const float* nzg = noise + (size_t)b * TT * NN;
  const float* ug  = u + (size_t)b * TT * NIN;
  float* outB = out + (size_t)b * TT * NN;

  // ---- stage chunk 0 (latency hidden behind weight setup below)
#pragma unroll
  for (int i = 0; i < 8; ++i)
    __builtin_amdgcn_global_load_lds((gu32*)(nzg + i * 256 + l * 4),
                                     (lu32*)(&smNz[0][i * 256]), 16, 0, 0);
#pragma unroll
  for (int j = 0; j < 3; ++j)
    __builtin_amdgcn_global_load_lds((gu32*)(ug + j * 64 + l),
                                     (lu32*)(&smU[0][j * 64]), 4, 0, 0);

  // ---- weights: W_rec rows 4g..4g+3, cols 16h..16h+15, packed f16 pairs.
  v2h w16[4][8];
#pragma unroll
  for (int r = 0; r < 4; ++r) {
    const float* row = Wrec + (4 * g + r) * NN + 16 * h;
#pragma unroll
    for (int j4 = 0; j4 < 4; ++j4) {
      const v4f v = *reinterpret_cast<const v4f*>(row + 4 * j4);
      w16[r][2 * j4 + 0] = __builtin_amdgcn_cvt_pkrtz(v.x, v.y);
      w16[r][2 * j4 + 1] = __builtin_amdgcn_cvt_pkrtz(v.z, v.w);
    }
  }
  // u-bias weights: h<3 lanes handle u pair (2h, 2h+1); h==3 lane handles noise.
  const int hh = (h < 3) ? h : 0;  // safe address for h==3
  v2h winu[4];
#pragma unroll
  for (int r = 0; r < 4; ++r) {
    const float a0 = Win[(4 * g + r) * NIN + 2 * hh + 0];
    const float a1 = Win[(4 * g + r) * NIN + 2 * hh + 1];
    const v2h wp = __builtin_amdgcn_cvt_pkrtz(a0, a1);
    winu[r] = (h < 3) ? wp : v2h{(__fp16)0.0f, (__fp16)0.0f};
  }

  // bpermute addresses (loop-invariant): sK[2q+e] comes from lane
  // l' = 16h + 4q + (g&3)  (source group g' = 4h+q; any h' holds the copy).
  int baddr[4];
#pragma unroll
  for (int q = 0; q < 4; ++q) baddr[q] = 4 * (16 * h + 4 * q + (g & 3));

  float sOut[4] = {0.0f, 0.0f, 0.0f, 0.0f};  // s[4g..4g+3] (this lane's outputs)
  int sK[8];                                  // packed s[16h..16h+15]
#pragma unroll
  for (int j = 0; j < 8; ++j) sK[j] = 0;

  outB[l] = 0.0f;  // states[:,0,:] = 0

  // Drain once -> clean vmcnt accounting for the hand-counted waits below.
  asm volatile("s_waitcnt vmcnt(0)" ::: "memory");
  __builtin_amdgcn_sched_barrier(0);

  for (int c = 0; c < NCHUNK; ++c) {
    const int buf = c & 1;

    if (c + 1 < NCHUNK) {
      const float* ng = nzg + (size_t)(c + 1) * CHUNK * NN;
      const float* gg = ug + (size_t)(c + 1) * CHUNK * NIN;
      float* nl = &smNz[buf ^ 1][0];
      float* ul = &smU[buf ^ 1][0];
#pragma unroll
      for (int i = 0; i < 8; ++i)
        __builtin_amdgcn_global_load_lds((gu32*)(ng + i * 256 + l * 4),
                                         (lu32*)(nl + i * 256), 16, 0, 0);
#pragma unroll
      for (int j = 0; j < 3; ++j)
        __builtin_amdgcn_global_load_lds((gu32*)(gg + j * 64 + l),
                                         (lu32*)(ul + j * 64), 4, 0, 0);
      // Outstanding (oldest->newest): 11 loads(chunk c) + 8 stores(chunk c-1
      // epilogue) + 11 loads(chunk c+1); vmcnt retires in issue order.
      asm volatile("s_waitcnt vmcnt(19)" ::: "memory");
    } else {
      asm volatile("s_waitcnt vmcnt(8)" ::: "memory");
    }
    __builtin_amdgcn_sched_barrier(0);

    const float* nzB = &smNz[buf][4 * g];       // per-lane noise base (b128)
    const float* uB  = &smU[buf][2 * hh];       // per-lane u base (b64)

#pragma unroll 4
    for (int st = 0; st < CHUNK; ++st) {
      // ---- bias partials (staged-LDS only; off the recurrence chain)
      const v4f nz4 = *reinterpret_cast<const v4f*>(nzB + st * NN);
      const v2f u2  = *reinterpret_cast<const v2f*>(uB + st * NIN);
      const v2h u2h = __builtin_amdgcn_cvt_pkrtz(u2.x, u2.y);
      float partial[4];
#pragma unroll
      for (int r = 0; r < 4; ++r) {
        const float nb = (h == 3) ? SCALE * nz4[r] : 0.0f;
        partial[r] = __builtin_amdgcn_fdot2(u2h, winu[r], nb, false);
      }

      // ---- main dots: 4 output rows x 8 packed k-pairs (VGPRxVGPR)
#pragma unroll
      for (int j = 0; j < 8; ++j) {
        const v2h sj = h2_from_i(sK[j]);
#pragma unroll
        for (int r = 0; r < 4; ++r)
          partial[r] = __builtin_amdgcn_fdot2(sj, w16[r][j], partial[r], false);
      }

      // ---- reduce across h (quad): xor1 then xor2, pure DPP
#pragma unroll
      for (int r = 0; r < 4; ++r) partial[r] += dppf<0xB1>(partial[r]);
#pragma unroll
      for (int r = 0; r < 4; ++r) partial[r] += dppf<0x4E>(partial[r]);

      // ---- relu + lerp (local: sOut is this lane's own previous output)
#pragma unroll
      for (int r = 0; r < 4; ++r) {
        const float rr = fmaxf(partial[r], 0.0f);
        sOut[r] = fmaf(0.2f, rr, 0.8f * sOut[r]);
      }

      // ---- store path: lane l writes component n = 4g+h = l (select by h)
      {
        const float va = (h & 1) ? sOut[1] : sOut[0];
        const float vb = (h & 1) ? sOut[3] : sOut[2];
        smHist[st][l] = (h & 2) ? vb : va;
      }

      // ---- pack + one-hop redistribution for next step's k-slice
      const int pk01 = i_from_h2(__builtin_amdgcn_cvt_pkrtz(sOut[0], sOut[1]));
      const int pk23 = i_from_h2(__builtin_amdgcn_cvt_pkrtz(sOut[2], sOut[3]));
#pragma unroll
      for (int q = 0; q < 4; ++q) {
        sK[2 * q + 0] = __builtin_amdgcn_ds_bpermute(baddr[q], pk01);
        sK[2 * q + 1] = __builtin_amdgcn_ds_bpermute(baddr[q], pk23);
      }
    }

    // ---- chunk epilogue: dump 32 state rows (output rows 32c+1..32c+32).
    v4f st4[8];
    const float* hbase = &smHist[0][0] + (l >> 4) * NN + (l & 15) * 4;
#pragma unroll
    for (int i = 0; i < 8; ++i)
      st4[i] = *(const v4f*)(hbase + i * 4 * NN);       // 8x ds_read_b128

    float* gp = outB + (size_t)(c * CHUNK + 1) * NN + (l >> 4) * NN + (l & 15) * 4;
    if (c + 1 < NCHUNK) {
#pragma unroll
      for (int i = 0; i < 8; ++i)
        *(v4f*)(gp + (size_t)i * 4 * NN) = st4[i];      // 8x store_dwordx4
    } else {
      // last chunk: rows 993..1023 only (row 1024 doesn't exist)
#pragma unroll
      for (int i = 0; i < 7; ++i)
        *(v4f*)(gp + (size_t)i * 4 * NN) = st4[i];
      if (l < 48)  // rows 1021..1023
        *(v4f*)(gp + (size_t)7 * 4 * NN) = st4[7];
    }
  }
}

extern "C" void kernel_launch(void* const* d_in, const int* in_sizes, int n_in,
                              void* d_out, int out_size, void* d_ws, size_t ws_size,
                              hipStream_t stream) {
  const float* u     = (const float*)d_in[0];
  const float* noise = (const float*)d_in[1];
  const float* Wrec  = (const float*)d_in[2];
  const float* Win   = (const float*)d_in[3];
  float* out = (float*)d_out;

  const int B = in_sizes[0] / (TT * NIN);  // 512
  hipLaunchKernelGGL(rnn_scan_kernel, dim3(B), dim3(64), 0, stream,
                     u, noise, Wrec, Win, out);
}